// Round 3
// baseline (394.235 us; speedup 1.0000x reference)
//
#include <hip/hip_runtime.h>
#include <hip/hip_bf16.h>

// Problem constants
#define LNUM 8
#define ENUM 8
#define DDIM 256
#define BSZ  16384
#define H1N  64
#define H2N  32

#define BT   64     // rows per block
#define NTHR 512    // 8 waves

// LDS pitches (u16 elements); odd 16B-granule strides -> conflict-light
#define PX   264    // x tile (D + 8)
#define PH1  72     // h1 tile (H1 + 8)
#define PH2  40     // h2 tile (H2 + 8)
#define PSW  9      // softmax weights pitch (floats)

// ws element offsets (u16 elems) for fragment-ordered weights
#define WS1_OFF 0           // 64 steps * 16384 elems
#define WS2_OFF 1048576     // 64 steps * 2048
#define WS3_OFF 1179648     // 64 steps * 8192

typedef float f32x4 __attribute__((ext_vector_type(4)));
typedef unsigned short u16x8 __attribute__((ext_vector_type(8)));
typedef __bf16 bf16x8 __attribute__((ext_vector_type(8)));

// Round-to-nearest-even f32 -> bf16 (truncation bias compounds over 24 GEMMs).
static __device__ __forceinline__ unsigned short f2bf(float f) {
    unsigned u = __builtin_bit_cast(unsigned, f);
    u += 0x7fffu + ((u >> 16) & 1u);
    return (unsigned short)(u >> 16);
}

static __device__ __forceinline__ f32x4 mfma16(u16x8 a, u16x8 b, f32x4 c) {
    return __builtin_amdgcn_mfma_f32_16x16x32_bf16(
        __builtin_bit_cast(bf16x8, a), __builtin_bit_cast(bf16x8, b), c, 0, 0, 0);
}

// ---------------------------------------------------------------------------
// Kernel 1: convert fp32 weights -> bf16 B-FRAGMENT layout in ws.
// A fragment = 64 lanes x 8 elems (16 B) contiguous; lane (q=lane>>4,r=lane&15)
// holds W[n = n0 + r][k = k0 + q*8 .. +7]. Fragment order matches moe_fused's
// read pattern so each wave loads its B operands with global_load_dwordx4
// directly from L1/L2 -- weights never touch LDS.
//   ws1: [s][nt(4)][kt(8)][512]   ws2: [s][n2(2)][kt(2)][512]   ws3: [s][nt(16)][512]
// ---------------------------------------------------------------------------
__global__ __launch_bounds__(256) void cvt_w_frag(
    const float* __restrict__ w1, const float* __restrict__ w2,
    const float* __restrict__ w3, unsigned short* __restrict__ ws)
{
    int gid = blockIdx.x * 256 + threadIdx.x;   // one u16x8 group
    const float* src;
    unsigned short* dst;
    if (gid < 131072) {                          // W1: [s][n(64)][k(256)]
        int s = gid >> 11, rem = gid & 2047;
        int nt = rem >> 9, r2 = rem & 511, kt = r2 >> 6, lane = r2 & 63;
        int n = nt * 16 + (lane & 15), k = kt * 32 + (lane >> 4) * 8;
        src = w1 + ((size_t)s * 16384 + n * 256 + k);
        dst = ws + WS1_OFF + (size_t)gid * 8;
    } else if (gid < 147456) {                   // W2: [s][n(32)][k(64)]
        int g = gid - 131072;
        int s = g >> 8, rem = g & 255;
        int n2 = rem >> 7, r2 = rem & 127, kt = r2 >> 6, lane = r2 & 63;
        int n = n2 * 16 + (lane & 15), k = kt * 32 + (lane >> 4) * 8;
        src = w2 + ((size_t)s * 2048 + n * 64 + k);
        dst = ws + WS2_OFF + (size_t)g * 8;
    } else {                                     // W3: [s][n(256)][k(32)]
        int g = gid - 147456;
        int s = g >> 10, rem = g & 1023;
        int nt = rem >> 6, lane = rem & 63;
        int n = nt * 16 + (lane & 15), k = (lane >> 4) * 8;
        src = w3 + ((size_t)s * 8192 + n * 32 + k);
        dst = ws + WS3_OFF + (size_t)g * 8;
    }
    float4 a = *(const float4*)src;
    float4 b = *(const float4*)(src + 4);
    u16x8 p;
    p[0] = f2bf(a.x); p[1] = f2bf(a.y); p[2] = f2bf(a.z); p[3] = f2bf(a.w);
    p[4] = f2bf(b.x); p[5] = f2bf(b.y); p[6] = f2bf(b.z); p[7] = f2bf(b.w);
    *(u16x8*)dst = p;
}

// ---------------------------------------------------------------------------
// Kernel 2: fused 8-layer x 8-expert MoE MLP.
// Block = 64 rows, 8 waves: (wm in {0,1}) 32-row half x (wn in {0..3}) column
// slice. x and the output accumulator live in registers; weights are read as
// pre-swizzled B-fragments straight from global (L1/L2-resident, coalesced
// dwordx4). LDS carries only the G1->G2 and G2->G3 transposes (double-
// buffered) -> 2 barriers/step, 76 KB LDS -> 2 blocks/CU (4 waves/SIMD).
// ---------------------------------------------------------------------------
__global__ __launch_bounds__(NTHR, 4) void moe_fused(
    const float* __restrict__ src, const unsigned short* __restrict__ Wf,
    const float* __restrict__ b1, const float* __restrict__ b2,
    const float* __restrict__ b3, const float* __restrict__ masks,
    float* __restrict__ out)
{
    __shared__ __align__(16) unsigned short Xlds[BT * PX];        // 33792 B
    __shared__ __align__(16) unsigned short H1lds[2][BT * PH1];   // 18432 B
    __shared__ __align__(16) unsigned short H2lds[2][BT * PH2];   // 10240 B
    __shared__ float SWlds[BT * PSW];                             //  2304 B
    __shared__ float B3lds[ENUM * DDIM];                          //  8192 B
    __shared__ float B1lds[ENUM * H1N];                           //  2048 B
    __shared__ float B2lds[ENUM * H2N];                           //  1024 B
    // total 76032 B -> 2 blocks/CU

    const int tid  = threadIdx.x;
    const int lane = tid & 63;
    const int w    = tid >> 6;
    const int wm   = w >> 2;        // {0,1}: 32-row half
    const int wn   = w & 3;         // {0..3}: column slice
    const int n15  = lane & 15;
    const int q    = lane >> 4;
    const int b0   = blockIdx.x * BT;
    const int mtG2 = wm * 2 + (wn >> 1);   // G2: 16-row tile {0..3}
    const int ncG2 = (wn & 1) * 16;        // G2: 16-col slice

    u16x8 xf[2][8];      // persistent x A-fragments: 2 M-subtiles x K=256
    f32x4 ACC[2][4];     // accumulator: 2 M-subtiles x 4 N-subtiles

    auto stage_layer = [&](int l) {
        if (tid < 64) {
            const float* mp = masks + ((size_t)l * BSZ + b0 + tid) * ENUM;
            float4 m0 = *(const float4*)mp;
            float4 m1 = *(const float4*)(mp + 4);
            float mv[8] = {m0.x, m0.y, m0.z, m0.w, m1.x, m1.y, m1.z, m1.w};
            float mx = mv[0];
            #pragma unroll
            for (int e = 1; e < 8; ++e) mx = fmaxf(mx, mv[e]);
            float s = 0.f;
            #pragma unroll
            for (int e = 0; e < 8; ++e) { mv[e] = expf(mv[e] - mx); s += mv[e]; }
            float inv = 1.f / s;
            #pragma unroll
            for (int e = 0; e < 8; ++e) SWlds[tid * PSW + e] = mv[e] * inv;
        }
        *(float4*)&B3lds[tid * 4] =
            *(const float4*)(b3 + (size_t)l * ENUM * DDIM + tid * 4);
        if (tid < 128)
            *(float4*)&B1lds[tid * 4] =
                *(const float4*)(b1 + (size_t)l * ENUM * H1N + tid * 4);
        if (tid < 64)
            *(float4*)&B2lds[tid * 4] =
                *(const float4*)(b2 + (size_t)l * ENUM * H2N + tid * 4);
    };

    // ACC = sum_e softmax_w[row][e] * b3[e][col]  (fp32 VALU, once per layer)
    auto acc_init = [&]() {
        #pragma unroll
        for (int mt = 0; mt < 2; ++mt)
            #pragma unroll
            for (int nt = 0; nt < 4; ++nt) ACC[mt][nt] = (f32x4){0.f,0.f,0.f,0.f};
        #pragma unroll 2
        for (int e2 = 0; e2 < ENUM; ++e2) {
            float swv[2][4];
            #pragma unroll
            for (int mt = 0; mt < 2; ++mt)
                #pragma unroll
                for (int rg = 0; rg < 4; ++rg)
                    swv[mt][rg] = SWlds[(wm*32 + mt*16 + q*4 + rg) * PSW + e2];
            #pragma unroll
            for (int nt = 0; nt < 4; ++nt) {
                float bv = B3lds[e2 * DDIM + wn*64 + nt*16 + n15];
                #pragma unroll
                for (int mt = 0; mt < 2; ++mt)
                    #pragma unroll
                    for (int rg = 0; rg < 4; ++rg)
                        ACC[mt][nt][rg] += swv[mt][rg] * bv;
            }
        }
    };

    auto xf_read = [&]() {
        #pragma unroll
        for (int mt = 0; mt < 2; ++mt)
            #pragma unroll
            for (int kt = 0; kt < 8; ++kt)
                xf[mt][kt] = *(const u16x8*)
                    &Xlds[(wm*32 + mt*16 + n15) * PX + q*8 + kt*32];
    };
    auto x_write = [&]() {
        #pragma unroll
        for (int mt = 0; mt < 2; ++mt)
            #pragma unroll
            for (int nt = 0; nt < 4; ++nt)
                #pragma unroll
                for (int rg = 0; rg < 4; ++rg)
                    Xlds[(wm*32 + mt*16 + q*4 + rg) * PX + wn*64 + nt*16 + n15] =
                        f2bf(ACC[mt][nt][rg]);
    };

    // ================= prologue =================
    #pragma unroll
    for (int i = 0; i < 4; ++i) {
        int o = (i * NTHR + tid) * 8;
        int r = o >> 8, c = o & 255;
        const float* p = src + (size_t)(b0 + r) * DDIM + c;
        float4 f0 = *(const float4*)(p);
        float4 f1 = *(const float4*)(p + 4);
        u16x8 pk;
        pk[0] = f2bf(f0.x); pk[1] = f2bf(f0.y); pk[2] = f2bf(f0.z); pk[3] = f2bf(f0.w);
        pk[4] = f2bf(f1.x); pk[5] = f2bf(f1.y); pk[6] = f2bf(f1.z); pk[7] = f2bf(f1.w);
        *(u16x8*)&Xlds[r * PX + c] = pk;
    }
    stage_layer(0);
    __syncthreads();
    xf_read();
    acc_init();

    // ================= fused expert-layer loop =================
    #pragma unroll 1
    for (int s = 0; s < LNUM * ENUM; ++s) {
        const int e = s & 7, l = s >> 3, pb = s & 1;
        const unsigned short* w1p = Wf + WS1_OFF + (size_t)s * 16384 + wn * 4096 + lane * 8;
        const unsigned short* w2p = Wf + WS2_OFF + (size_t)s * 2048 + (wn & 1) * 1024 + lane * 8;
        const unsigned short* w3p = Wf + WS3_OFF + (size_t)s * 8192 + wn * 2048 + lane * 8;

        // ---- G1: h1 = relu(x @ W1^T + b1); B-frags direct from global ----
        f32x4 a1[2] = {(f32x4){0.f,0.f,0.f,0.f}, (f32x4){0.f,0.f,0.f,0.f}};
        #pragma unroll
        for (int kt = 0; kt < 8; ++kt) {
            u16x8 bf = *(const u16x8*)(w1p + kt * 512);
            a1[0] = mfma16(xf[0][kt], bf, a1[0]);
            a1[1] = mfma16(xf[1][kt], bf, a1[1]);
        }
        {
            float bb = B1lds[e * H1N + wn*16 + n15];
            #pragma unroll
            for (int mt = 0; mt < 2; ++mt)
                #pragma unroll
                for (int rg = 0; rg < 4; ++rg) {
                    float v = fmaxf(a1[mt][rg] + bb, 0.f);
                    H1lds[pb][(wm*32 + mt*16 + q*4 + rg) * PH1 + wn*16 + n15] = f2bf(v);
                }
        }
        __syncthreads();                       // B1: h1[pb] ready

        // ---- G2: h2 = relu(h1 @ W2^T + b2) * softmax_w[row] ----
        f32x4 a2 = (f32x4){0.f, 0.f, 0.f, 0.f};
        #pragma unroll
        for (int kt = 0; kt < 2; ++kt) {
            u16x8 af = *(const u16x8*)&H1lds[pb][(mtG2*16 + n15) * PH1 + q*8 + kt*32];
            u16x8 bf = *(const u16x8*)(w2p + kt * 512);
            a2 = mfma16(af, bf, a2);
        }
        {
            float bb = B2lds[e * H2N + ncG2 + n15];
            #pragma unroll
            for (int rg = 0; rg < 4; ++rg) {
                int row = mtG2*16 + q*4 + rg;
                float v = fmaxf(a2[rg] + bb, 0.f) * SWlds[row * PSW + e];
                H2lds[pb][row * PH2 + ncG2 + n15] = f2bf(v);
            }
        }
        __syncthreads();                       // B2: h2[pb] ready

        // ---- G3: ACC += (w .* h2) @ W3^T (no trailing barrier) ----
        {
            u16x8 af0 = *(const u16x8*)&H2lds[pb][(wm*32 + n15) * PH2 + q*8];
            u16x8 af1 = *(const u16x8*)&H2lds[pb][(wm*32 + 16 + n15) * PH2 + q*8];
            #pragma unroll
            for (int nt = 0; nt < 4; ++nt) {
                u16x8 bf = *(const u16x8*)(w3p + nt * 512);
                ACC[0][nt] = mfma16(af0, bf, ACC[0][nt]);
                ACC[1][nt] = mfma16(af1, bf, ACC[1][nt]);
            }
        }

        // ---- layer transition ----
        if (e == 7 && l < LNUM - 1) {
            x_write();                         // Xlds untouched since last xf_read
            __syncthreads();                   // T1: x ready, all waves past G3
            xf_read();
            stage_layer(l + 1);
            __syncthreads();                   // T2: SW/biases ready
            acc_init();
        }
    }

    // ================= final store (fp32) =================
    #pragma unroll
    for (int mt = 0; mt < 2; ++mt)
        #pragma unroll
        for (int nt = 0; nt < 4; ++nt)
            #pragma unroll
            for (int rg = 0; rg < 4; ++rg)
                out[(size_t)(b0 + wm*32 + mt*16 + q*4 + rg) * DDIM
                    + wn*64 + nt*16 + n15] = ACC[mt][nt][rg];
}

extern "C" void kernel_launch(void* const* d_in, const int* in_sizes, int n_in,
                              void* d_out, int out_size, void* d_ws, size_t ws_size,
                              hipStream_t stream) {
    const float* src   = (const float*)d_in[0];
    const float* W1    = (const float*)d_in[1];
    const float* b1    = (const float*)d_in[2];
    const float* W2    = (const float*)d_in[3];
    const float* b2    = (const float*)d_in[4];
    const float* W3    = (const float*)d_in[5];
    const float* b3    = (const float*)d_in[6];
    const float* masks = (const float*)d_in[7];
    float* out = (float*)d_out;
    unsigned short* ws = (unsigned short*)d_ws;   // needs 3,407,872 B

    hipLaunchKernelGGL(cvt_w_frag, dim3(832), dim3(256), 0, stream, W1, W2, W3, ws);
    hipLaunchKernelGGL(moe_fused, dim3(BSZ / BT), dim3(NTHR), 0, stream,
                       src, ws, b1, b2, b3, masks, out);
}

// Round 4
// 199.248 us; speedup vs baseline: 1.9786x; 1.9786x over previous
//
#include <hip/hip_runtime.h>
#include <hip/hip_bf16.h>

// Problem constants
#define LNUM 8
#define ENUM 8
#define DDIM 256
#define BSZ  16384
#define H1N  64
#define H2N  32

#define BT   64     // rows per block
#define NTHR 512    // 8 waves

// LDS pitches (u16 elements); odd 16B-granule strides -> conflict-light
#define PX   264    // x tile (D + 8)
#define PH1  72     // h1 tile (H1 + 8)
#define PH2  40     // h2 tile (H2 + 8)
#define PSW  9      // softmax weights pitch (floats)

// ws element offsets (u16 elems) for fragment-ordered weights
#define WS1_OFF 0           // 64 steps * 16384 elems
#define WS2_OFF 1048576     // 64 steps * 2048
#define WS3_OFF 1179648     // 64 steps * 8192

typedef float f32x4 __attribute__((ext_vector_type(4)));
typedef unsigned short u16x8 __attribute__((ext_vector_type(8)));
typedef __bf16 bf16x8 __attribute__((ext_vector_type(8)));

#define Z4 ((f32x4){0.f, 0.f, 0.f, 0.f})

// Round-to-nearest-even f32 -> bf16 (truncation bias compounds over 24 GEMMs).
static __device__ __forceinline__ unsigned short f2bf(float f) {
    unsigned u = __builtin_bit_cast(unsigned, f);
    u += 0x7fffu + ((u >> 16) & 1u);
    return (unsigned short)(u >> 16);
}

static __device__ __forceinline__ f32x4 mfma16(u16x8 a, u16x8 b, f32x4 c) {
    return __builtin_amdgcn_mfma_f32_16x16x32_bf16(
        __builtin_bit_cast(bf16x8, a), __builtin_bit_cast(bf16x8, b), c, 0, 0, 0);
}

// ---------------------------------------------------------------------------
// Kernel 1: fp32 weights -> bf16 B-fragment layout. COALESCED reads (thread =
// 8 consecutive k of one row), scattered 16B fragment writes (L2 merges).
// Fragment: 64 lanes x 8 elems; slot (q*16+r) holds W[n0+r][k0+q*8 .. +7].
// ---------------------------------------------------------------------------
__global__ __launch_bounds__(256) void cvt_w_frag(
    const float* __restrict__ w1, const float* __restrict__ w2,
    const float* __restrict__ w3, unsigned short* __restrict__ ws)
{
    int gid = blockIdx.x * 256 + threadIdx.x;
    const float* src;
    unsigned short* dst;
    if (gid < 131072) {                          // W1: [s][n(64)][k(256)]
        int s = gid >> 11, rem = gid & 2047;
        int n = rem >> 5, kc = rem & 31;
        int nt = n >> 4, r = n & 15, kt = kc >> 2, q = kc & 3;
        src = w1 + (size_t)gid * 8;
        dst = ws + WS1_OFF + (size_t)s * 16384 + nt * 4096 + kt * 512 + (q * 16 + r) * 8;
    } else if (gid < 147456) {                   // W2: [s][n(32)][k(64)]
        int g = gid - 131072;
        int s = g >> 8, rem = g & 255;
        int n = rem >> 3, kc = rem & 7;
        int n2 = n >> 4, r = n & 15, kt = kc >> 2, q = kc & 3;
        src = w2 + (size_t)g * 8;
        dst = ws + WS2_OFF + (size_t)s * 2048 + n2 * 1024 + kt * 512 + (q * 16 + r) * 8;
    } else {                                     // W3: [s][n(256)][k(32)]
        int g = gid - 147456;
        int s = g >> 10, rem = g & 1023;
        int n = rem >> 2, q = rem & 3;
        int nt = n >> 4, r = n & 15;
        src = w3 + (size_t)g * 8;
        dst = ws + WS3_OFF + (size_t)s * 8192 + nt * 512 + (q * 16 + r) * 8;
    }
    float4 a = *(const float4*)src;
    float4 b = *(const float4*)(src + 4);
    u16x8 p;
    p[0] = f2bf(a.x); p[1] = f2bf(a.y); p[2] = f2bf(a.z); p[3] = f2bf(a.w);
    p[4] = f2bf(b.x); p[5] = f2bf(b.y); p[6] = f2bf(b.z); p[7] = f2bf(b.w);
    *(u16x8*)dst = p;
}

// ---------------------------------------------------------------------------
// Kernel 2: fused 8-layer x 8-expert MoE MLP.
// launch_bounds(512,2): 256-reg budget -- NO spills (R3's (512,4) spilled xf,
// +13MB scratch writes, 2.2x regression). Weights read as pre-swizzled
// B-fragments from global/L2; W1 frags double-buffered in REGISTERS and
// prefetched one step ahead so the vmcnt(0) barrier drain lands after they
// are already covered by G1 compute. LDS only holds x + h1/h2 transposes
// (63.3 KB; biases read directly from global L1).
// ---------------------------------------------------------------------------
__global__ __launch_bounds__(NTHR, 2) void moe_fused(
    const float* __restrict__ src, const unsigned short* __restrict__ Wf,
    const float* __restrict__ b1, const float* __restrict__ b2,
    const float* __restrict__ b3, const float* __restrict__ masks,
    float* __restrict__ out)
{
    __shared__ __align__(16) unsigned short Xlds[BT * PX];        // 33792 B
    __shared__ __align__(16) unsigned short H1lds[2][BT * PH1];   // 18432 B
    __shared__ __align__(16) unsigned short H2lds[2][BT * PH2];   // 10240 B
    __shared__ float SWlds[BT * PSW];                             //  2304 B
    // total 64768 B

    const int tid  = threadIdx.x;
    const int lane = tid & 63;
    const int w    = tid >> 6;
    const int wm   = w >> 2;        // {0,1}: 32-row half
    const int wn   = w & 3;         // {0..3}: column slice
    const int n15  = lane & 15;
    const int q    = lane >> 4;
    const int b0   = blockIdx.x * BT;
    const int mtG2 = wm * 2 + (wn >> 1);   // G2: 16-row tile
    const int ncG2 = (wn & 1) * 16;        // G2: 16-col slice

    const unsigned short* w1base = Wf + WS1_OFF + wn * 4096 + lane * 8;
    const unsigned short* w2base = Wf + WS2_OFF + (wn & 1) * 1024 + lane * 8;
    const unsigned short* w3base = Wf + WS3_OFF + wn * 2048 + lane * 8;

    u16x8 xf[2][8];          // persistent x A-frags: 2 M-subtiles x K=256
    f32x4 ACC[2][4];         // output accumulator
    u16x8 wf0[8], wf1[8];    // W1 B-frag register double buffer
    u16x8 w2f[2], w3f[4];    // current-step W2/W3 B-frags

    auto stage_softmax = [&](int l) {
        if (tid < 64) {
            const float* mp = masks + ((size_t)l * BSZ + b0 + tid) * ENUM;
            float4 m0 = *(const float4*)mp;
            float4 m1 = *(const float4*)(mp + 4);
            float mv[8] = {m0.x, m0.y, m0.z, m0.w, m1.x, m1.y, m1.z, m1.w};
            float mx = mv[0];
            #pragma unroll
            for (int e = 1; e < 8; ++e) mx = fmaxf(mx, mv[e]);
            float s = 0.f;
            #pragma unroll
            for (int e = 0; e < 8; ++e) { mv[e] = expf(mv[e] - mx); s += mv[e]; }
            float inv = 1.f / s;
            #pragma unroll
            for (int e = 0; e < 8; ++e) SWlds[tid * PSW + e] = mv[e] * inv;
        }
    };

    // ACC = sum_e softmax_w[row][e] * b3[e][col]  (fp32 VALU, once per layer)
    auto acc_init = [&](int l) {
        const float* b3l = b3 + (size_t)l * ENUM * DDIM;
        #pragma unroll
        for (int mt = 0; mt < 2; ++mt)
            #pragma unroll
            for (int nt = 0; nt < 4; ++nt) ACC[mt][nt] = Z4;
        #pragma unroll 2
        for (int e2 = 0; e2 < ENUM; ++e2) {
            float swv[2][4];
            #pragma unroll
            for (int mt = 0; mt < 2; ++mt)
                #pragma unroll
                for (int rg = 0; rg < 4; ++rg)
                    swv[mt][rg] = SWlds[(wm*32 + mt*16 + q*4 + rg) * PSW + e2];
            #pragma unroll
            for (int nt = 0; nt < 4; ++nt) {
                float bv = b3l[e2 * DDIM + wn*64 + nt*16 + n15];
                #pragma unroll
                for (int mt = 0; mt < 2; ++mt)
                    #pragma unroll
                    for (int rg = 0; rg < 4; ++rg)
                        ACC[mt][nt][rg] += swv[mt][rg] * bv;
            }
        }
    };

    auto xf_read = [&]() {
        #pragma unroll
        for (int mt = 0; mt < 2; ++mt)
            #pragma unroll
            for (int kt = 0; kt < 8; ++kt)
                xf[mt][kt] = *(const u16x8*)
                    &Xlds[(wm*32 + mt*16 + n15) * PX + q*8 + kt*32];
    };
    auto x_write = [&]() {
        #pragma unroll
        for (int mt = 0; mt < 2; ++mt)
            #pragma unroll
            for (int nt = 0; nt < 4; ++nt)
                #pragma unroll
                for (int rg = 0; rg < 4; ++rg)
                    Xlds[(wm*32 + mt*16 + q*4 + rg) * PX + wn*64 + nt*16 + n15] =
                        f2bf(ACC[mt][nt][rg]);
    };

    // ================= prologue =================
    #pragma unroll
    for (int kt = 0; kt < 8; ++kt)               // W1 frags for s=0
        wf0[kt] = *(const u16x8*)(w1base + kt * 512);

    #pragma unroll
    for (int i = 0; i < 4; ++i) {                // stage layer-0 x (bf16)
        int o = (i * NTHR + tid) * 8;
        int r = o >> 8, c = o & 255;
        const float* p = src + (size_t)(b0 + r) * DDIM + c;
        float4 f0 = *(const float4*)(p);
        float4 f1 = *(const float4*)(p + 4);
        u16x8 pk;
        pk[0] = f2bf(f0.x); pk[1] = f2bf(f0.y); pk[2] = f2bf(f0.z); pk[3] = f2bf(f0.w);
        pk[4] = f2bf(f1.x); pk[5] = f2bf(f1.y); pk[6] = f2bf(f1.z); pk[7] = f2bf(f1.w);
        *(u16x8*)&Xlds[r * PX + c] = pk;
    }
    stage_softmax(0);
    __syncthreads();
    xf_read();
    acc_init(0);

// ================= one expert step =================
#define STEP(S, WFC, WFN)                                                      \
  {                                                                            \
    const int s_ = (S);                                                        \
    const int e_ = s_ & 7, l_ = s_ >> 3, pb_ = s_ & 1;                         \
    if (s_ < 63) {            /* prefetch NEXT step's W1 frags into regs */    \
      const unsigned short* p1 = w1base + (size_t)(s_ + 1) * 16384;            \
      _Pragma("unroll")                                                        \
      for (int kt = 0; kt < 8; ++kt) WFN[kt] = *(const u16x8*)(p1 + kt * 512); \
    }                                                                          \
    {                         /* this step's W2/W3 frags (used post-barrier) */\
      const unsigned short* p2 = w2base + (size_t)s_ * 2048;                   \
      w2f[0] = *(const u16x8*)(p2);                                            \
      w2f[1] = *(const u16x8*)(p2 + 512);                                      \
      const unsigned short* p3 = w3base + (size_t)s_ * 8192;                   \
      _Pragma("unroll")                                                        \
      for (int nt = 0; nt < 4; ++nt) w3f[nt] = *(const u16x8*)(p3 + nt * 512); \
    }                                                                          \
    const float bb1 = b1[s_ * 64 + wn * 16 + n15];                             \
    const float bb2 = b2[s_ * 32 + ncG2 + n15];                                \
    /* G1: h1 = relu(x @ W1^T + b1), 4 independent MFMA chains */              \
    f32x4 a1[2][2] = {{Z4, Z4}, {Z4, Z4}};                                     \
    _Pragma("unroll")                                                          \
    for (int kt = 0; kt < 4; ++kt) {                                           \
      a1[0][0] = mfma16(xf[0][kt],     WFC[kt],     a1[0][0]);                 \
      a1[1][0] = mfma16(xf[1][kt],     WFC[kt],     a1[1][0]);                 \
      a1[0][1] = mfma16(xf[0][kt + 4], WFC[kt + 4], a1[0][1]);                 \
      a1[1][1] = mfma16(xf[1][kt + 4], WFC[kt + 4], a1[1][1]);                 \
    }                                                                          \
    _Pragma("unroll")                                                          \
    for (int mt = 0; mt < 2; ++mt)                                             \
      _Pragma("unroll")                                                        \
      for (int rg = 0; rg < 4; ++rg) {                                         \
        float v = fmaxf(a1[mt][0][rg] + a1[mt][1][rg] + bb1, 0.f);             \
        H1lds[pb_][(wm*32 + mt*16 + q*4 + rg) * PH1 + wn*16 + n15] = f2bf(v);  \
      }                                                                        \
    __syncthreads();                        /* B1: h1 ready; prefetches done */\
    /* G2: h2 = relu(h1 @ W2^T + b2) * softmax_w */                            \
    f32x4 a2 = Z4;                                                             \
    {                                                                          \
      u16x8 af0 = *(const u16x8*)&H1lds[pb_][(mtG2*16 + n15) * PH1 + q*8];     \
      u16x8 af1 = *(const u16x8*)&H1lds[pb_][(mtG2*16 + n15) * PH1 + q*8 + 32];\
      a2 = mfma16(af0, w2f[0], a2);                                            \
      a2 = mfma16(af1, w2f[1], a2);                                            \
    }                                                                          \
    _Pragma("unroll")                                                          \
    for (int rg = 0; rg < 4; ++rg) {                                           \
      int row = mtG2*16 + q*4 + rg;                                            \
      float v = fmaxf(a2[rg] + bb2, 0.f) * SWlds[row * PSW + e_];              \
      H2lds[pb_][row * PH2 + ncG2 + n15] = f2bf(v);                            \
    }                                                                          \
    __syncthreads();                        /* B2: h2 ready */                 \
    /* G3: ACC += (w .* h2) @ W3^T */                                          \
    {                                                                          \
      u16x8 af0 = *(const u16x8*)&H2lds[pb_][(wm*32 + n15) * PH2 + q*8];       \
      u16x8 af1 = *(const u16x8*)&H2lds[pb_][(wm*32 + 16 + n15) * PH2 + q*8];  \
      _Pragma("unroll")                                                        \
      for (int nt = 0; nt < 4; ++nt) {                                         \
        ACC[0][nt] = mfma16(af0, w3f[nt], ACC[0][nt]);                         \
        ACC[1][nt] = mfma16(af1, w3f[nt], ACC[1][nt]);                         \
      }                                                                        \
    }                                                                          \
    if (e_ == 7 && l_ < LNUM - 1) {         /* layer transition */             \
      x_write();                                                               \
      __syncthreads();                                                         \
      xf_read();                                                               \
      stage_softmax(l_ + 1);                                                   \
      __syncthreads();                                                         \
      acc_init(l_ + 1);                                                        \
    }                                                                          \
  }

    #pragma unroll 1
    for (int s2 = 0; s2 < LNUM * ENUM; s2 += 2) {
        STEP(s2,     wf0, wf1)
        STEP(s2 + 1, wf1, wf0)
    }
#undef STEP

    // ================= final store (fp32) =================
    #pragma unroll
    for (int mt = 0; mt < 2; ++mt)
        #pragma unroll
        for (int nt = 0; nt < 4; ++nt)
            #pragma unroll
            for (int rg = 0; rg < 4; ++rg)
                out[(size_t)(b0 + wm*32 + mt*16 + q*4 + rg) * DDIM
                    + wn*64 + nt*16 + n15] = ACC[mt][nt][rg];
}

extern "C" void kernel_launch(void* const* d_in, const int* in_sizes, int n_in,
                              void* d_out, int out_size, void* d_ws, size_t ws_size,
                              hipStream_t stream) {
    const float* src   = (const float*)d_in[0];
    const float* W1    = (const float*)d_in[1];
    const float* b1    = (const float*)d_in[2];
    const float* W2    = (const float*)d_in[3];
    const float* b2    = (const float*)d_in[4];
    const float* W3    = (const float*)d_in[5];
    const float* b3    = (const float*)d_in[6];
    const float* masks = (const float*)d_in[7];
    float* out = (float*)d_out;
    unsigned short* ws = (unsigned short*)d_ws;   // needs 3,407,872 B

    hipLaunchKernelGGL(cvt_w_frag, dim3(832), dim3(256), 0, stream, W1, W2, W3, ws);
    hipLaunchKernelGGL(moe_fused, dim3(BSZ / BT), dim3(NTHR), 0, stream,
                       src, ws, b1, b2, b3, masks, out);
}

// Round 5
// 191.030 us; speedup vs baseline: 2.0637x; 1.0430x over previous
//
#include <hip/hip_runtime.h>
#include <hip/hip_bf16.h>

// Problem constants
#define LNUM 8
#define ENUM 8
#define DDIM 256
#define BSZ  16384
#define H1N  64
#define H2N  32

#define BT   64     // rows per block
#define NTHR 512    // 8 waves

// LDS pitches (u16 elements); odd 16B-granule strides -> conflict-light
#define PX   264    // x tile (D + 8)
#define PH1  72     // h1T tile (H1 + 8)   [row][feat]
#define PH2  40     // h2T tile (H2 + 8)   [row][feat]
#define PSW  9      // softmax weights pitch (floats)

// ws element offsets (u16 elems) for fragment-ordered weights
#define WS1_OFF 0           // 64 steps * 16384 elems
#define WS2_OFF 1048576     // 64 steps * 2048
#define WS3_OFF 1179648     // 64 steps * 8192

typedef float f32x4 __attribute__((ext_vector_type(4)));
typedef unsigned short u16x8 __attribute__((ext_vector_type(8)));
typedef unsigned short u16x4 __attribute__((ext_vector_type(4)));
typedef __bf16 bf16x8 __attribute__((ext_vector_type(8)));

#define Z4 ((f32x4){0.f, 0.f, 0.f, 0.f})

// Round-to-nearest-even f32 -> bf16 (truncation bias compounds over 24 GEMMs).
static __device__ __forceinline__ unsigned short f2bf(float f) {
    unsigned u = __builtin_bit_cast(unsigned, f);
    u += 0x7fffu + ((u >> 16) & 1u);
    return (unsigned short)(u >> 16);
}

// D[m][n] = sum_k A[m][k]*B[n][k] + C : A supplies m, B supplies n, frags are
// symmetric [idx16][K] -> swapping args transposes the output tile.
static __device__ __forceinline__ f32x4 mfma16(u16x8 a, u16x8 b, f32x4 c) {
    return __builtin_amdgcn_mfma_f32_16x16x32_bf16(
        __builtin_bit_cast(bf16x8, a), __builtin_bit_cast(bf16x8, b), c, 0, 0, 0);
}

// ---------------------------------------------------------------------------
// Kernel 1: fp32 weights -> bf16 B-fragment layout. Coalesced reads,
// scattered 16B fragment writes (L2 merges).
// Fragment: 64 lanes x 8 elems; slot (q*16+r) holds W[n0+r][k0+q*8 .. +7].
// ---------------------------------------------------------------------------
__global__ __launch_bounds__(256) void cvt_w_frag(
    const float* __restrict__ w1, const float* __restrict__ w2,
    const float* __restrict__ w3, unsigned short* __restrict__ ws)
{
    int gid = blockIdx.x * 256 + threadIdx.x;
    const float* src;
    unsigned short* dst;
    if (gid < 131072) {                          // W1: [s][n(64)][k(256)]
        int s = gid >> 11, rem = gid & 2047;
        int n = rem >> 5, kc = rem & 31;
        int nt = n >> 4, r = n & 15, kt = kc >> 2, q = kc & 3;
        src = w1 + (size_t)gid * 8;
        dst = ws + WS1_OFF + (size_t)s * 16384 + nt * 4096 + kt * 512 + (q * 16 + r) * 8;
    } else if (gid < 147456) {                   // W2: [s][n(32)][k(64)]
        int g = gid - 131072;
        int s = g >> 8, rem = g & 255;
        int n = rem >> 3, kc = rem & 7;
        int n2 = n >> 4, r = n & 15, kt = kc >> 2, q = kc & 3;
        src = w2 + (size_t)g * 8;
        dst = ws + WS2_OFF + (size_t)s * 2048 + n2 * 1024 + kt * 512 + (q * 16 + r) * 8;
    } else {                                     // W3: [s][n(256)][k(32)]
        int g = gid - 147456;
        int s = g >> 10, rem = g & 1023;
        int n = rem >> 2, q = rem & 3;
        int nt = n >> 4, r = n & 15;
        src = w3 + (size_t)g * 8;
        dst = ws + WS3_OFF + (size_t)s * 8192 + nt * 512 + (q * 16 + r) * 8;
    }
    float4 a = *(const float4*)src;
    float4 b = *(const float4*)(src + 4);
    u16x8 p;
    p[0] = f2bf(a.x); p[1] = f2bf(a.y); p[2] = f2bf(a.z); p[3] = f2bf(a.w);
    p[4] = f2bf(b.x); p[5] = f2bf(b.y); p[6] = f2bf(b.z); p[7] = f2bf(b.w);
    *(u16x8*)dst = p;
}

// ---------------------------------------------------------------------------
// Kernel 2: fused 8-layer x 8-expert MoE MLP, 2-expert supersteps.
// G1/G2 computed TRANSPOSED (A=weights, B=activations) so each lane's 4
// C-regs hold 4 consecutive features -> epilogue is 1 ds_write_b64 per tile;
// G2/G3 read activations back as b128 A/B-frags from [row][feat] LDS tiles.
// 2 experts between barriers: 2 barriers per superstep (1 per expert).
// ---------------------------------------------------------------------------
__global__ __launch_bounds__(NTHR, 2) void moe_fused(
    const float* __restrict__ src, const unsigned short* __restrict__ Wf,
    const float* __restrict__ b1, const float* __restrict__ b2,
    const float* __restrict__ b3, const float* __restrict__ masks,
    float* __restrict__ out)
{
    __shared__ __align__(16) unsigned short Xlds[BT * PX];        // 33792 B
    __shared__ __align__(16) unsigned short H1T[2][BT * PH1];     // 18432 B [row][feat]
    __shared__ __align__(16) unsigned short H2T[2][BT * PH2];     // 10240 B [row][feat]
    __shared__ float SWlds[BT * PSW];                             //  2304 B
    // total 64768 B

    const int tid  = threadIdx.x;
    const int lane = tid & 63;
    const int w    = tid >> 6;
    const int wm   = w >> 2;        // {0,1}
    const int wn   = w & 3;         // {0..3}
    const int n15  = lane & 15;
    const int q    = lane >> 4;
    const int b0   = blockIdx.x * BT;

    const unsigned short* w1base = Wf + WS1_OFF + wn * 4096 + lane * 8;  // feat grp wn
    const unsigned short* w2base = Wf + WS2_OFF + wm * 1024 + lane * 8;  // feat grp wm
    const unsigned short* w3base = Wf + WS3_OFF + wn * 2048 + lane * 8;  // out grp wn

    u16x8 xf[2][8];          // persistent x B-frags: rows wm*32+mt*16, K=256
    f32x4 ACC[2][4];         // output accumulator (C-layout: row=q*4+rg, col=n15)

    auto stage_softmax = [&](int l) {
        if (tid < 64) {
            const float* mp = masks + ((size_t)l * BSZ + b0 + tid) * ENUM;
            float4 m0 = *(const float4*)mp;
            float4 m1 = *(const float4*)(mp + 4);
            float mv[8] = {m0.x, m0.y, m0.z, m0.w, m1.x, m1.y, m1.z, m1.w};
            float mx = mv[0];
            #pragma unroll
            for (int e = 1; e < 8; ++e) mx = fmaxf(mx, mv[e]);
            float s = 0.f;
            #pragma unroll
            for (int e = 0; e < 8; ++e) { mv[e] = expf(mv[e] - mx); s += mv[e]; }
            float inv = 1.f / s;
            #pragma unroll
            for (int e = 0; e < 8; ++e) SWlds[tid * PSW + e] = mv[e] * inv;
        }
    };

    // ACC = sum_e softmax_w[row][e] * b3[e][col]  (fp32 VALU, once per layer)
    auto acc_init = [&](int l) {
        const float* b3l = b3 + (size_t)l * ENUM * DDIM;
        #pragma unroll
        for (int mt = 0; mt < 2; ++mt)
            #pragma unroll
            for (int nt = 0; nt < 4; ++nt) ACC[mt][nt] = Z4;
        #pragma unroll 2
        for (int e2 = 0; e2 < ENUM; ++e2) {
            float swv[2][4];
            #pragma unroll
            for (int mt = 0; mt < 2; ++mt)
                #pragma unroll
                for (int rg = 0; rg < 4; ++rg)
                    swv[mt][rg] = SWlds[(wm*32 + mt*16 + q*4 + rg) * PSW + e2];
            #pragma unroll
            for (int nt = 0; nt < 4; ++nt) {
                float bv = b3l[e2 * DDIM + wn*64 + nt*16 + n15];
                #pragma unroll
                for (int mt = 0; mt < 2; ++mt)
                    #pragma unroll
                    for (int rg = 0; rg < 4; ++rg)
                        ACC[mt][nt][rg] += swv[mt][rg] * bv;
            }
        }
    };

    auto xf_read = [&]() {
        #pragma unroll
        for (int mt = 0; mt < 2; ++mt)
            #pragma unroll
            for (int kt = 0; kt < 8; ++kt)
                xf[mt][kt] = *(const u16x8*)
                    &Xlds[(wm*32 + mt*16 + n15) * PX + q*8 + kt*32];
    };
    auto x_write = [&]() {
        #pragma unroll
        for (int mt = 0; mt < 2; ++mt)
            #pragma unroll
            for (int nt = 0; nt < 4; ++nt)
                #pragma unroll
                for (int rg = 0; rg < 4; ++rg)
                    Xlds[(wm*32 + mt*16 + q*4 + rg) * PX + wn*64 + nt*16 + n15] =
                        f2bf(ACC[mt][nt][rg]);
    };

    // ================= prologue =================
    #pragma unroll
    for (int i = 0; i < 4; ++i) {                // stage layer-0 x (bf16)
        int o = (i * NTHR + tid) * 8;
        int r = o >> 8, c = o & 255;
        const float* p = src + (size_t)(b0 + r) * DDIM + c;
        float4 f0 = *(const float4*)(p);
        float4 f1 = *(const float4*)(p + 4);
        u16x8 pk;
        pk[0] = f2bf(f0.x); pk[1] = f2bf(f0.y); pk[2] = f2bf(f0.z); pk[3] = f2bf(f0.w);
        pk[4] = f2bf(f1.x); pk[5] = f2bf(f1.y); pk[6] = f2bf(f1.z); pk[7] = f2bf(f1.w);
        *(u16x8*)&Xlds[r * PX + c] = pk;
    }
    stage_softmax(0);
    __syncthreads();
    xf_read();
    acc_init(0);

    // ================= superstep loop: 2 experts per iteration =================
    #pragma unroll 1
    for (int ss = 0; ss < LNUM * ENUM / 2; ++ss) {
        const int s0 = 2 * ss, s1 = s0 + 1;
        const int l  = s0 >> 3, e0 = s0 & 7, e1 = s1 & 7;

        // ---- superstep-top loads: W1 both experts, W2 both, biases ----
        u16x8 wfA[8], wfB[8], w2A[2], w2B[2];
        {
            const unsigned short* pA = w1base + (size_t)s0 * 16384;
            const unsigned short* pB = w1base + (size_t)s1 * 16384;
            #pragma unroll
            for (int kt = 0; kt < 8; ++kt) {
                wfA[kt] = *(const u16x8*)(pA + kt * 512);
                wfB[kt] = *(const u16x8*)(pB + kt * 512);
            }
            const unsigned short* q2A = w2base + (size_t)s0 * 2048;
            const unsigned short* q2B = w2base + (size_t)s1 * 2048;
            w2A[0] = *(const u16x8*)(q2A);  w2A[1] = *(const u16x8*)(q2A + 512);
            w2B[0] = *(const u16x8*)(q2B);  w2B[1] = *(const u16x8*)(q2B + 512);
        }
        const float4 bb1A = *(const float4*)(b1 + s0 * 64 + wn * 16 + q * 4);
        const float4 bb1B = *(const float4*)(b1 + s1 * 64 + wn * 16 + q * 4);
        const float4 bb2A = *(const float4*)(b2 + s0 * 32 + wm * 16 + q * 4);
        const float4 bb2B = *(const float4*)(b2 + s1 * 32 + wm * 16 + q * 4);

        // ---- G1 both experts (transposed): lane -> feats wn*16+q*4+rg ----
        // 4 independent chains; B-frag xf shared by both experts.
        f32x4 a1A[2] = {Z4, Z4}, a1B[2] = {Z4, Z4};
        #pragma unroll
        for (int kt = 0; kt < 8; ++kt) {
            a1A[0] = mfma16(wfA[kt], xf[0][kt], a1A[0]);
            a1A[1] = mfma16(wfA[kt], xf[1][kt], a1A[1]);
            a1B[0] = mfma16(wfB[kt], xf[0][kt], a1B[0]);
            a1B[1] = mfma16(wfB[kt], xf[1][kt], a1B[1]);
        }

        // ---- W3 loads here (wf regs dead): used after B2, well covered ----
        u16x8 w3A[4], w3B[4];
        {
            const unsigned short* p3A = w3base + (size_t)s0 * 8192;
            const unsigned short* p3B = w3base + (size_t)s1 * 8192;
            #pragma unroll
            for (int nt = 0; nt < 4; ++nt) {
                w3A[nt] = *(const u16x8*)(p3A + nt * 512);
                w3B[nt] = *(const u16x8*)(p3B + nt * 512);
            }
        }

        // ---- G1 epilogues: relu+bias, pack 4 feats -> one b64 per (mt,expert) ----
        #pragma unroll
        for (int mt = 0; mt < 2; ++mt) {
            u16x4 pkA, pkB;
            #pragma unroll
            for (int rg = 0; rg < 4; ++rg) {
                pkA[rg] = f2bf(fmaxf(a1A[mt][rg] + bb1A[rg], 0.f));
                pkB[rg] = f2bf(fmaxf(a1B[mt][rg] + bb1B[rg], 0.f));
            }
            int row = wm*32 + mt*16 + n15;
            *(u16x4*)&H1T[0][row * PH1 + wn*16 + q*4] = pkA;
            *(u16x4*)&H1T[1][row * PH1 + wn*16 + q*4] = pkB;
        }
        __syncthreads();                    // B1: h1 for both experts ready

        // ---- G2 both experts (transposed): lane -> h2 feats wm*16+q*4+rg,
        //      row group wn ----
        f32x4 a2A = Z4, a2B = Z4;
        {
            u16x8 hA0 = *(const u16x8*)&H1T[0][(wn*16 + n15) * PH1 + q*8];
            u16x8 hA1 = *(const u16x8*)&H1T[0][(wn*16 + n15) * PH1 + q*8 + 32];
            u16x8 hB0 = *(const u16x8*)&H1T[1][(wn*16 + n15) * PH1 + q*8];
            u16x8 hB1 = *(const u16x8*)&H1T[1][(wn*16 + n15) * PH1 + q*8 + 32];
            a2A = mfma16(w2A[0], hA0, a2A);
            a2B = mfma16(w2B[0], hB0, a2B);
            a2A = mfma16(w2A[1], hA1, a2A);
            a2B = mfma16(w2B[1], hB1, a2B);
        }
        {
            int row = wn*16 + n15;
            float swA = SWlds[row * PSW + e0];
            float swB = SWlds[row * PSW + e1];
            u16x4 pkA, pkB;
            #pragma unroll
            for (int rg = 0; rg < 4; ++rg) {
                pkA[rg] = f2bf(fmaxf(a2A[rg] + bb2A[rg], 0.f) * swA);
                pkB[rg] = f2bf(fmaxf(a2B[rg] + bb2B[rg], 0.f) * swB);
            }
            *(u16x4*)&H2T[0][row * PH2 + wm*16 + q*4] = pkA;
            *(u16x4*)&H2T[1][row * PH2 + wm*16 + q*4] = pkB;
        }
        __syncthreads();                    // B2: h2 for both experts ready

        // ---- G3 both experts: ACC += h2 @ W3^T (8 independent chains) ----
        {
            u16x8 hA0 = *(const u16x8*)&H2T[0][(wm*32 + n15) * PH2 + q*8];
            u16x8 hA1 = *(const u16x8*)&H2T[0][(wm*32 + 16 + n15) * PH2 + q*8];
            u16x8 hB0 = *(const u16x8*)&H2T[1][(wm*32 + n15) * PH2 + q*8];
            u16x8 hB1 = *(const u16x8*)&H2T[1][(wm*32 + 16 + n15) * PH2 + q*8];
            #pragma unroll
            for (int nt = 0; nt < 4; ++nt) {
                ACC[0][nt] = mfma16(hA0, w3A[nt], ACC[0][nt]);
                ACC[1][nt] = mfma16(hA1, w3A[nt], ACC[1][nt]);
            }
            #pragma unroll
            for (int nt = 0; nt < 4; ++nt) {
                ACC[0][nt] = mfma16(hB0, w3B[nt], ACC[0][nt]);
                ACC[1][nt] = mfma16(hB1, w3B[nt], ACC[1][nt]);
            }
        }

        // ---- layer transition (e1 == 7 always lands at superstep end) ----
        if (e1 == 7 && l < LNUM - 1) {
            x_write();
            __syncthreads();
            xf_read();
            stage_softmax(l + 1);
            __syncthreads();
            acc_init(l + 1);
        }
    }

    // ================= final store (fp32) =================
    #pragma unroll
    for (int mt = 0; mt < 2; ++mt)
        #pragma unroll
        for (int nt = 0; nt < 4; ++nt)
            #pragma unroll
            for (int rg = 0; rg < 4; ++rg)
                out[(size_t)(b0 + wm*32 + mt*16 + q*4 + rg) * DDIM
                    + wn*64 + nt*16 + n15] = ACC[mt][nt][rg];
}

extern "C" void kernel_launch(void* const* d_in, const int* in_sizes, int n_in,
                              void* d_out, int out_size, void* d_ws, size_t ws_size,
                              hipStream_t stream) {
    const float* src   = (const float*)d_in[0];
    const float* W1    = (const float*)d_in[1];
    const float* b1    = (const float*)d_in[2];
    const float* W2    = (const float*)d_in[3];
    const float* b2    = (const float*)d_in[4];
    const float* W3    = (const float*)d_in[5];
    const float* b3    = (const float*)d_in[6];
    const float* masks = (const float*)d_in[7];
    float* out = (float*)d_out;
    unsigned short* ws = (unsigned short*)d_ws;   // needs 3,407,872 B

    hipLaunchKernelGGL(cvt_w_frag, dim3(832), dim3(256), 0, stream, W1, W2, W3, ws);
    hipLaunchKernelGGL(moe_fused, dim3(BSZ / BT), dim3(NTHR), 0, stream,
                       src, ws, b1, b2, b3, masks, out);
}